// Round 7
// baseline (265.457 us; speedup 1.0000x reference)
//
#include <hip/hip_runtime.h>
#include <hip/hip_bf16.h>

typedef __bf16 bf16x8 __attribute__((ext_vector_type(8)));
typedef float f32x4 __attribute__((ext_vector_type(4)));

#define M_TOK 16384   // 8 * 2048 tokens
#define CHUNK 64
#define NCHUNK 32     // 2048 / 64

__device__ __forceinline__ void gload16(const void* g, void* l) {
    __builtin_amdgcn_global_load_lds(
        (const __attribute__((address_space(1))) void*)g,
        (__attribute__((address_space(3))) void*)l, 16, 0, 0);
}

__device__ __forceinline__ float sigmoidf_(float v) { return 1.f / (1.f + __expf(-v)); }

#define BARRIER __builtin_amdgcn_s_barrier()
#define LGKM0 asm volatile("s_waitcnt lgkmcnt(0)" ::: "memory")   // plain: no sched_barrier (m141)
#define VMC(n) asm volatile("s_waitcnt vmcnt(" #n ")" ::: "memory")

// ---------------- fp32 -> bf16 bulk convert (vectorized) ----------------
__global__ __launch_bounds__(256) void f32_to_bf16_k(const float* __restrict__ in,
                                                     __hip_bfloat16* __restrict__ out, int n8) {
    int i = blockIdx.x * 256 + threadIdx.x;
    if (i >= n8) return;
    const f32x4* p4 = reinterpret_cast<const f32x4*>(in) + (size_t)i * 2;
    f32x4 a = p4[0], b = p4[1];
    union { __hip_bfloat16 h[8]; uint4 u; } o;
    o.h[0] = __float2bfloat16(a[0]); o.h[1] = __float2bfloat16(a[1]);
    o.h[2] = __float2bfloat16(a[2]); o.h[3] = __float2bfloat16(a[3]);
    o.h[4] = __float2bfloat16(b[0]); o.h[5] = __float2bfloat16(b[1]);
    o.h[6] = __float2bfloat16(b[2]); o.h[7] = __float2bfloat16(b[3]);
    *reinterpret_cast<uint4*>(out + (size_t)i * 8) = o.u;
}

// ---------------- all 6 weight converts in ONE launch (blockIdx.y selects tensor) ----------------
__global__ __launch_bounds__(256)
void wconv6(const float* s0, const float* s1, const float* s2, const float* s3,
            const float* s4, const float* s5,
            __hip_bfloat16* d0, __hip_bfloat16* d1, __hip_bfloat16* d2,
            __hip_bfloat16* d3, __hip_bfloat16* d4, __hip_bfloat16* d5,
            int n0, int n1, int n2, int n3, int n4, int n5) {
    const float* src; __hip_bfloat16* dst; int n8;
    switch (blockIdx.y) {
        case 0: src = s0; dst = d0; n8 = n0; break;
        case 1: src = s1; dst = d1; n8 = n1; break;
        case 2: src = s2; dst = d2; n8 = n2; break;
        case 3: src = s3; dst = d3; n8 = n3; break;
        case 4: src = s4; dst = d4; n8 = n4; break;
        default: src = s5; dst = d5; n8 = n5; break;
    }
    int i = blockIdx.x * 256 + threadIdx.x;
    if (i >= n8) return;
    const f32x4* p4 = reinterpret_cast<const f32x4*>(src) + (size_t)i * 2;
    f32x4 a = p4[0], b = p4[1];
    union { __hip_bfloat16 h[8]; uint4 u; } o;
    o.h[0] = __float2bfloat16(a[0]); o.h[1] = __float2bfloat16(a[1]);
    o.h[2] = __float2bfloat16(a[2]); o.h[3] = __float2bfloat16(a[3]);
    o.h[4] = __float2bfloat16(b[0]); o.h[5] = __float2bfloat16(b[1]);
    o.h[6] = __float2bfloat16(b[2]); o.h[7] = __float2bfloat16(b[3]);
    *reinterpret_cast<uint4*>(dst + (size_t)i * 8) = o.u;
}

// ---------------- stage one half-tile (128 rows x 64 cols bf16), pre-swizzled source ----------------
// Swizzle (G4-verified, R5: conflicts -> 0): logical (r, colbyte c) lives at LDS byte
// r*128 + (c ^ ((r&7)<<4)). gload_lds writes linearly -> SOURCE col pre-XORed (involution).
__device__ __forceinline__ void stage_half(const __hip_bfloat16* src, int ldk, size_t row0,
                                           int k0, char* lds_half, int tid) {
    const int lane = tid & 63, wid = tid >> 6;
    #pragma unroll
    for (int l = 0; l < 2; ++l) {
        int q = wid * 2 + l;                 // 0..15 (1 KB chunk)
        int r = q * 8 + (lane >> 3);         // row within half
        int cb = ((lane & 7) * 16) ^ ((r & 7) << 4);   // pre-swizzled source col byte
        const char* g = (const char*)(src + (row0 + r) * (size_t)ldk + k0) + cb;
        gload16(g, lds_half + q * 1024 + lane * 16);
    }
}

// ================= 256x256 GEMM, 8-phase/K-tile (T3+T4+T5), counted vmcnt =========
// MODE 0: silu -> bf16 (N=512)  | MODE 1: sigmoid -> bf16 (N=1024)
// MODE 2: (X@W^T + b + HS@CW^T + b2) * gate -> f32 (N=1024, K=1024+128)
//
// Per tile kt, 4 phases = C-quadrants. Phase p: {ds_read subtile for p's MFMA
// (issued under p-1's MFMA of other waves) ; stage 1 half of kt+1 ; vmcnt(counted) ;
// BARRIER ; lgkmcnt(0) ; setprio(1) 16 MFMA setprio(0) ; BARRIER}.
// Derived waits (2 loads/stage): steady vmcnt(4)@P0/P1/P3, none@P2; last tile 2/0/-.
// Every waited load is >=2 phases old; 4-6 loads always in flight (never drain to 0).
#define READ_A(ARR, MOFF)                                                      \
    { _Pragma("unroll") for (int m_ = 0; m_ < 4; ++m_)                         \
      _Pragma("unroll") for (int kk_ = 0; kk_ < 2; ++kk_)                      \
          ARR[m_][kk_] = frag(Ab, ((MOFF) + m_) * 32 + wm16 + lr, kk_); }
#define READ_B(ARR, NOFF)                                                      \
    { _Pragma("unroll") for (int n_ = 0; n_ < 2; ++n_)                         \
      _Pragma("unroll") for (int kk_ = 0; kk_ < 2; ++kk_)                      \
          ARR[n_][kk_] = frag(Bb_, ((NOFF) + n_) * 64 + wn16 + lr, kk_); }
#define MFMA_Q(A, B, MB, NB)                                                   \
    { _Pragma("unroll") for (int kk_ = 0; kk_ < 2; ++kk_)                      \
      _Pragma("unroll") for (int m_ = 0; m_ < 4; ++m_)                         \
      _Pragma("unroll") for (int n_ = 0; n_ < 2; ++n_)                         \
          acc[(MB) + m_][(NB) + n_] = __builtin_amdgcn_mfma_f32_16x16x32_bf16( \
              A[m_][kk_], B[n_][kk_], acc[(MB) + m_][(NB) + n_], 0, 0, 0); }
#define SETP1 __builtin_amdgcn_s_setprio(1)
#define SETP0 __builtin_amdgcn_s_setprio(0)
#define TILE_BODY(KT, STG, W0, W1, W3)                                         \
    {                                                                          \
        char* Ab  = smem + (((KT) & 1) ? 65536 : 0);                           \
        char* Bb_ = Ab + 32768;                                                \
        /* P0 */                                                               \
        READ_A(aH, 0); READ_B(bLo, 0);                                         \
        if (STG) stage(KT + 1, 0);                                             \
        W0; BARRIER; LGKM0;                                                    \
        SETP1; MFMA_Q(aH, bLo, 0, 0); SETP0;                                   \
        BARRIER;                                                               \
        /* P1 */                                                               \
        READ_A(aC, 4);                                                         \
        if (STG) stage(KT + 1, 1);                                             \
        W1; BARRIER; LGKM0;                                                    \
        SETP1; MFMA_Q(aC, bLo, 4, 0); SETP0;                                   \
        BARRIER;                                                               \
        /* P2 */                                                               \
        READ_B(bHi, 2);                                                        \
        if (STG) stage(KT + 1, 2);                                             \
        BARRIER; LGKM0;                                                        \
        SETP1; MFMA_Q(aC, bHi, 4, 2); SETP0;                                   \
        BARRIER;                                                               \
        /* P3 (no reads: aH, bHi held) */                                      \
        if (STG) stage(KT + 1, 3);                                             \
        W3; BARRIER;                                                           \
        SETP1; MFMA_Q(aH, bHi, 0, 2); SETP0;                                   \
        BARRIER;                                                               \
    }

template<int MODE>
__global__ __launch_bounds__(512, 2)
void gemm256(const __hip_bfloat16* __restrict__ X, const __hip_bfloat16* __restrict__ W,
             const float* __restrict__ bias, const float* __restrict__ bias2,
             const __hip_bfloat16* __restrict__ HS, const __hip_bfloat16* __restrict__ CW,
             const __hip_bfloat16* __restrict__ gate, float* __restrict__ outF,
             __hip_bfloat16* __restrict__ outB) {
    __shared__ char smem[131072];                 // 2 buffers x (A[256][64] + B[256][64]) bf16
    constexpr int N  = (MODE == 0) ? 512 : 1024;
    constexpr int NT = (MODE == 2) ? 18 : 16;     // MODE2: 16 K-tiles X@W + 2 K-tiles HS@CW
    constexpr int nN = N / 256;

    const int nwg  = gridDim.x;
    const int orig = blockIdx.x;
    const int v    = (orig & 7) * (nwg >> 3) + (orig >> 3);   // XCD-bijective (nwg%8==0)
    const size_t m0 = (size_t)(v / nN) * 256;
    const int    n0 = (v % nN) * 256;
    const int tid = threadIdx.x, lane = tid & 63, wid = tid >> 6;
    const int wm = wid >> 2, wn = wid & 3;
    const int lr = lane & 15, lg = lane >> 4;
    const int wm16 = wm * 16, wn16 = wn * 16;

    auto frag = [&](const char* base, int R, int kk2) -> bf16x8 {
        int cb = (kk2 * 64 + lg * 16) ^ ((R & 7) << 4);
        return *reinterpret_cast<const bf16x8*>(base + R * 128 + cb);
    };
    auto stage = [&](int kt, int half) {
        char* buf = smem + ((kt & 1) ? 65536 : 0);
        bool cp = (MODE == 2) && (kt >= 16);
        const __hip_bfloat16* a = cp ? HS : X;
        const __hip_bfloat16* b = cp ? CW : W;
        int ldk = cp ? 128 : 1024;
        int k0  = cp ? (kt - 16) * 64 : kt * 64;
        switch (half) {
            case 0: stage_half(a, ldk, m0,             k0, buf,                 tid); break;
            case 1: stage_half(b, ldk, (size_t)n0,     k0, buf + 32768,         tid); break;
            case 2: stage_half(a, ldk, m0 + 128,       k0, buf + 16384,         tid); break;
            default: stage_half(b, ldk, (size_t)n0 + 128, k0, buf + 32768 + 16384, tid); break;
        }
    };

    f32x4 acc[8][4] = {};
    bf16x8 aH[4][2], aC[4][2], bLo[2][2], bHi[2][2];

    // prologue: stage tile 0 (h0..h3), wait h0,h1 landed, align
    stage(0, 0); stage(0, 1); stage(0, 2); stage(0, 3);
    VMC(4);
    BARRIER;

    for (int kt = 0; kt < NT - 1; ++kt)
        TILE_BODY(kt, true, VMC(4), VMC(4), VMC(4))
    TILE_BODY(NT - 1, false, VMC(2), VMC(0), (void)0)

    // epilogue
    #pragma unroll
    for (int m = 0; m < 8; ++m)
        #pragma unroll
        for (int n = 0; n < 4; ++n)
            #pragma unroll
            for (int rr = 0; rr < 4; ++rr) {
                size_t row = m0 + m * 32 + wm16 + lg * 4 + rr;
                int col = n0 + n * 64 + wn16 + lr;
                float vv = acc[m][n][rr] + bias[col];
                if constexpr (MODE == 0) {
                    outB[row * N + col] = __float2bfloat16(vv * sigmoidf_(vv));
                } else if constexpr (MODE == 1) {
                    outB[row * N + col] = __float2bfloat16(sigmoidf_(vv));
                } else {
                    float y = vv + bias2[col];
                    float gv = __bfloat162float(gate[row * 1024 + col]);
                    outF[row * 1024 + col] = y * gv;
                }
            }
}

// ---------------- u = (x@B_w^T + B_b) * sigmoid(z1@s_w2^T + s_b2)   [16384,128] ----------------
__global__ __launch_bounds__(256)
void gemm_u(const __hip_bfloat16* __restrict__ Z1, const __hip_bfloat16* __restrict__ W2,
            const float* __restrict__ b2,
            const __hip_bfloat16* __restrict__ X, const __hip_bfloat16* __restrict__ Bw,
            const float* __restrict__ Bb, __hip_bfloat16* __restrict__ U) {
    __shared__ __align__(16) char As[64 * 128];    // 64 rows x 128 B
    __shared__ __align__(16) char Bs[128 * 128];   // 128 rows x 128 B
    const int orig = blockIdx.x;                 // nwg = 256
    const int v = (orig & 7) * 32 + (orig >> 3);
    const int m0 = v * 64;
    const int tid = threadIdx.x;
    const int wid = tid >> 6, lane = tid & 63;
    const int wm = wid >> 1, wn = wid & 1;
    const int lr = lane & 15, lg = lane >> 4;
    const int srow = tid >> 3, sc8 = tid & 7;

    auto fragA = [&](int R, int kk) -> bf16x8 {
        int cb = (kk * 64 + lg * 16) ^ ((R & 7) << 4);
        return *reinterpret_cast<const bf16x8*>(As + R * 128 + cb);
    };
    auto fragB = [&](int R, int kk) -> bf16x8 {
        int cb = (kk * 64 + lg * 16) ^ ((R & 7) << 4);
        return *reinterpret_cast<const bf16x8*>(Bs + R * 128 + cb);
    };

    f32x4 accS[2][4] = {};
    for (int k0 = 0; k0 < 512; k0 += 64) {
        __syncthreads();
        #pragma unroll
        for (int j = 0; j < 2; ++j) {
            int row = srow + j * 32, q = tid + 256 * j;
            int cb = (sc8 * 16) ^ ((row & 7) << 4);
            gload16((const char*)&Z1[(size_t)(m0 + row) * 512 + k0] + cb, As + q * 16);
        }
        #pragma unroll
        for (int j = 0; j < 4; ++j) {
            int row = srow + j * 32, q = tid + 256 * j;
            int cb = (sc8 * 16) ^ ((row & 7) << 4);
            gload16((const char*)&W2[(size_t)row * 512 + k0] + cb, Bs + q * 16);
        }
        __syncthreads();
        #pragma unroll
        for (int kk = 0; kk < 2; ++kk) {
            bf16x8 af[2], bfr[4];
            #pragma unroll
            for (int m = 0; m < 2; ++m) af[m] = fragA(wm*32 + m*16 + lr, kk);
            #pragma unroll
            for (int n = 0; n < 4; ++n) bfr[n] = fragB(wn*64 + n*16 + lr, kk);
            #pragma unroll
            for (int m = 0; m < 2; ++m)
                #pragma unroll
                for (int n = 0; n < 4; ++n)
                    accS[m][n] = __builtin_amdgcn_mfma_f32_16x16x32_bf16(af[m], bfr[n], accS[m][n], 0, 0, 0);
        }
    }
    #pragma unroll
    for (int m = 0; m < 2; ++m)
        #pragma unroll
        for (int n = 0; n < 4; ++n)
            #pragma unroll
            for (int r = 0; r < 4; ++r) {
                int col = wn*64 + n*16 + lr;
                accS[m][n][r] = sigmoidf_(accS[m][n][r] + b2[col]);
            }
    f32x4 accU[2][4] = {};
    for (int k0 = 0; k0 < 1024; k0 += 64) {
        __syncthreads();
        #pragma unroll
        for (int j = 0; j < 2; ++j) {
            int row = srow + j * 32, q = tid + 256 * j;
            int cb = (sc8 * 16) ^ ((row & 7) << 4);
            gload16((const char*)&X[(size_t)(m0 + row) * 1024 + k0] + cb, As + q * 16);
        }
        #pragma unroll
        for (int j = 0; j < 4; ++j) {
            int row = srow + j * 32, q = tid + 256 * j;
            int cb = (sc8 * 16) ^ ((row & 7) << 4);
            gload16((const char*)&Bw[(size_t)row * 1024 + k0] + cb, Bs + q * 16);
        }
        __syncthreads();
        #pragma unroll
        for (int kk = 0; kk < 2; ++kk) {
            bf16x8 af[2], bfr[4];
            #pragma unroll
            for (int m = 0; m < 2; ++m) af[m] = fragA(wm*32 + m*16 + lr, kk);
            #pragma unroll
            for (int n = 0; n < 4; ++n) bfr[n] = fragB(wn*64 + n*16 + lr, kk);
            #pragma unroll
            for (int m = 0; m < 2; ++m)
                #pragma unroll
                for (int n = 0; n < 4; ++n)
                    accU[m][n] = __builtin_amdgcn_mfma_f32_16x16x32_bf16(af[m], bfr[n], accU[m][n], 0, 0, 0);
        }
    }
    #pragma unroll
    for (int m = 0; m < 2; ++m)
        #pragma unroll
        for (int n = 0; n < 4; ++n)
            #pragma unroll
            for (int r = 0; r < 4; ++r) {
                int row = m0 + wm*32 + m*16 + lg*4 + r;
                int col = wn*64 + n*16 + lr;
                float uval = (accU[m][n][r] + Bb[col]) * accS[m][n][r];
                U[(size_t)row * 128 + col] = __float2bfloat16(uval);
            }
}

// ---------------- P^8 column-wise: block j computes col j via 7 matvecs (fp32 exact) ---------
__global__ __launch_bounds__(128) void matpow8(const float* __restrict__ P,
                                               float* __restrict__ O) {
    __shared__ float Pl[128 * 132];
    __shared__ __align__(16) float v[2][128];
    const int tid = threadIdx.x, j = blockIdx.x;
    #pragma unroll 8
    for (int r = 0; r < 128; ++r) Pl[r * 132 + tid] = P[r * 128 + tid];
    v[0][tid] = P[tid * 128 + j];    // column j
    __syncthreads();
    int cur = 0;
    for (int it = 0; it < 7; ++it) {
        const f32x4* row = reinterpret_cast<const f32x4*>(&Pl[tid * 132]);
        const f32x4* hv  = reinterpret_cast<const f32x4*>(v[cur]);
        f32x4 s4 = {0.f, 0.f, 0.f, 0.f};
        #pragma unroll
        for (int k = 0; k < 32; ++k) s4 += row[k] * hv[k];
        v[cur ^ 1][tid] = s4[0] + s4[1] + s4[2] + s4[3];
        __syncthreads();
        cur ^= 1;
    }
    O[tid * 128 + j] = v[cur][tid];
}

// ---------------- chunked scan phase 1: local chunk-end states (zero init) ----------------
__global__ __launch_bounds__(128) void ssm_phase1(const float* __restrict__ A,
                                                  const __hip_bfloat16* __restrict__ u,
                                                  float* __restrict__ E) {
    __shared__ float Al[128 * 132];
    __shared__ __align__(16) float hbuf[2][128];
    const int tid = threadIdx.x;
    #pragma unroll 8
    for (int r = 0; r < 128; ++r) Al[r * 132 + tid] = A[r * 128 + tid];
    hbuf[0][tid] = 0.f;
    __syncthreads();
    const int b = blockIdx.x >> 5, c = blockIdx.x & 31;
    const __hip_bfloat16* up = u + ((size_t)b * 2048 + c * CHUNK) * 128;
    const f32x4* Arow = reinterpret_cast<const f32x4*>(&Al[tid * 132]);
    int cur = 0;
    for (int t = 0; t < CHUNK; ++t) {
        const f32x4* hv = reinterpret_cast<const f32x4*>(hbuf[cur]);
        f32x4 s4 = {0.f, 0.f, 0.f, 0.f};
        #pragma unroll
        for (int k = 0; k < 32; ++k) s4 += Arow[k] * hv[k];
        float val = s4[0] + s4[1] + s4[2] + s4[3] + __bfloat162float(up[t * 128 + tid]);
        hbuf[cur ^ 1][tid] = val;
        __syncthreads();
        cur ^= 1;
    }
    E[(size_t)blockIdx.x * 128 + tid] = hbuf[cur][tid];
}

// ---------------- phase 2: per-batch sequential combine across chunks with A^64 ----------------
__global__ __launch_bounds__(128) void ssm_phase2(const float* __restrict__ A64,
                                                  const float* __restrict__ E,
                                                  float* __restrict__ starts) {
    __shared__ float Al[128 * 132];
    __shared__ __align__(16) float st[2][128];
    const int tid = threadIdx.x;
    const int b = blockIdx.x;     // 8 blocks, one per batch
    #pragma unroll 8
    for (int r = 0; r < 128; ++r) Al[r * 132 + tid] = A64[r * 128 + tid];
    st[0][tid] = 0.f;
    __syncthreads();
    const f32x4* Arow = reinterpret_cast<const f32x4*>(&Al[tid * 132]);
    int cur = 0;
    for (int c = 0; c < NCHUNK; ++c) {
        starts[((size_t)b * NCHUNK + c) * 128 + tid] = st[cur][tid];
        const f32x4* hv = reinterpret_cast<const f32x4*>(st[cur]);
        f32x4 s4 = {0.f, 0.f, 0.f, 0.f};
        #pragma unroll
        for (int k = 0; k < 32; ++k) s4 += Arow[k] * hv[k];
        float val = s4[0] + s4[1] + s4[2] + s4[3] + E[((size_t)b * NCHUNK + c) * 128 + tid];
        st[cur ^ 1][tid] = val;
        __syncthreads();
        cur ^= 1;
    }
}

// ---------------- phase 3: re-run local scans from correct starts, emit hs (bf16) ----------------
__global__ __launch_bounds__(128) void ssm_phase3(const float* __restrict__ A,
                                                  const __hip_bfloat16* __restrict__ u,
                                                  const float* __restrict__ starts,
                                                  __hip_bfloat16* __restrict__ hs) {
    __shared__ float Al[128 * 132];
    __shared__ __align__(16) float hbuf[2][128];
    const int tid = threadIdx.x;
    #pragma unroll 8
    for (int r = 0; r < 128; ++r) Al[r * 132 + tid] = A[r * 128 + tid];
    hbuf[0][tid] = starts[(size_t)blockIdx.x * 128 + tid];
    __syncthreads();
    const int b = blockIdx.x >> 5, c = blockIdx.x & 31;
    const size_t tok0 = (size_t)b * 2048 + c * CHUNK;
    const __hip_bfloat16* up = u + tok0 * 128;
    const f32x4* Arow = reinterpret_cast<const f32x4*>(&Al[tid * 132]);
    int cur = 0;
    for (int t = 0; t < CHUNK; ++t) {
        const f32x4* hv = reinterpret_cast<const f32x4*>(hbuf[cur]);
        f32x4 s4 = {0.f, 0.f, 0.f, 0.f};
        #pragma unroll
        for (int k = 0; k < 32; ++k) s4 += Arow[k] * hv[k];
        float val = s4[0] + s4[1] + s4[2] + s4[3] + __bfloat162float(up[t * 128 + tid]);
        hs[(tok0 + t) * 128 + tid] = __float2bfloat16(val);
        hbuf[cur ^ 1][tid] = val;
        __syncthreads();
        cur ^= 1;
    }
}

// ---------------- host ----------------
extern "C" void kernel_launch(void* const* d_in, const int* in_sizes, int n_in,
                              void* d_out, int out_size, void* d_ws, size_t ws_size,
                              hipStream_t stream) {
    const float* x    = (const float*)d_in[0];
    const float* A    = (const float*)d_in[1];
    const float* B_w  = (const float*)d_in[2];
    const float* B_b  = (const float*)d_in[3];
    const float* C_w  = (const float*)d_in[4];
    const float* C_b  = (const float*)d_in[5];
    const float* D_w  = (const float*)d_in[6];
    const float* D_b  = (const float*)d_in[7];
    const float* s_w1 = (const float*)d_in[8];
    const float* s_b1 = (const float*)d_in[9];
    const float* s_w2 = (const float*)d_in[10];
    const float* s_b2 = (const float*)d_in[11];
    const float* g_w  = (const float*)d_in[12];
    const float* g_b  = (const float*)d_in[13];
    float* out = (float*)d_out;

    char* p = (char*)d_ws;
    auto alloc = [&](size_t n) { char* r = p; p += (n + 255) & ~(size_t)255; return r; };
    __hip_bfloat16* xb    = (__hip_bfloat16*)alloc((size_t)M_TOK * 1024 * 2);
    __hip_bfloat16* w1b   = (__hip_bfloat16*)alloc(512 * 1024 * 2);
    __hip_bfloat16* w2b   = (__hip_bfloat16*)alloc(128 * 512 * 2);
    __hip_bfloat16* Bwb   = (__hip_bfloat16*)alloc(128 * 1024 * 2);
    __hip_bfloat16* Cwb   = (__hip_bfloat16*)alloc(1024 * 128 * 2);
    __hip_bfloat16* Dwb   = (__hip_bfloat16*)alloc(1024 * 1024 * 2);
    __hip_bfloat16* gwb   = (__hip_bfloat16*)alloc(1024 * 1024 * 2);
    __hip_bfloat16* z1b   = (__hip_bfloat16*)alloc((size_t)M_TOK * 512 * 2);
    __hip_bfloat16* ub    = (__hip_bfloat16*)alloc((size_t)M_TOK * 128 * 2);
    __hip_bfloat16* hsb   = (__hip_bfloat16*)alloc((size_t)M_TOK * 128 * 2);
    __hip_bfloat16* gateb = (__hip_bfloat16*)alloc((size_t)M_TOK * 1024 * 2);
    float* pa       = (float*)alloc(128 * 128 * 4);
    float* pb       = (float*)alloc(128 * 128 * 4);
    float* Ebuf     = (float*)alloc(256 * 128 * 4);
    float* startbuf = (float*)alloc(256 * 128 * 4);

    // A^64 = (A^8)^8 via two column-matvec kernels (fp32 exact)
    matpow8<<<128, 128, 0, stream>>>(A,  pa);   // A^8
    matpow8<<<128, 128, 0, stream>>>(pa, pb);   // A^64

    // x -> bf16
    f32_to_bf16_k<<<dim3((M_TOK * 1024 / 8 + 255) / 256), dim3(256), 0, stream>>>(
        x, xb, M_TOK * 1024 / 8);
    // all weight converts, one launch
    wconv6<<<dim3(512, 6), dim3(256), 0, stream>>>(
        s_w1, s_w2, B_w, C_w, D_w, g_w,
        w1b, w2b, Bwb, Cwb, Dwb, gwb,
        512 * 1024 / 8, 128 * 512 / 8, 128 * 1024 / 8, 1024 * 128 / 8,
        1024 * 1024 / 8, 1024 * 1024 / 8);

    // z1 = silu(x @ s_w1^T + s_b1)
    gemm256<0><<<dim3(128), dim3(512), 0, stream>>>(
        xb, w1b, s_b1, nullptr, nullptr, nullptr, nullptr, nullptr, z1b);
    // u = (x @ B_w^T + B_b) * sigmoid(z1 @ s_w2^T + s_b2)
    gemm_u<<<dim3(256), dim3(256), 0, stream>>>(z1b, w2b, s_b2, xb, Bwb, B_b, ub);

    // chunked scan
    ssm_phase1<<<256, 128, 0, stream>>>(A, ub, Ebuf);
    ssm_phase2<<<8, 128, 0, stream>>>(pb, Ebuf, startbuf);
    ssm_phase3<<<256, 128, 0, stream>>>(A, ub, startbuf, hsb);

    // gate = sigmoid(x @ g_w^T + g_b)  (bf16 buffer)
    gemm256<1><<<dim3(256), dim3(512), 0, stream>>>(
        xb, gwb, g_b, nullptr, nullptr, nullptr, nullptr, nullptr, gateb);
    // out = (x @ D_w^T + D_b + hs @ C_w^T + C_b) * gate
    gemm256<2><<<dim3(256), dim3(512), 0, stream>>>(
        xb, Dwb, D_b, C_b, hsb, Cwb, gateb, out, nullptr);
}

// Round 8
// 239.423 us; speedup vs baseline: 1.1087x; 1.1087x over previous
//
#include <hip/hip_runtime.h>
#include <hip/hip_bf16.h>

typedef __bf16 bf16x8 __attribute__((ext_vector_type(8)));
typedef float f32x4 __attribute__((ext_vector_type(4)));

#define M_TOK 16384   // 8 * 2048 tokens
#define CHUNK 64
#define NCHUNK 32     // 2048 / 64

__device__ __forceinline__ void gload16(const void* g, void* l) {
    __builtin_amdgcn_global_load_lds(
        (const __attribute__((address_space(1))) void*)g,
        (__attribute__((address_space(3))) void*)l, 16, 0, 0);
}

__device__ __forceinline__ float sigmoidf_(float v) { return 1.f / (1.f + __expf(-v)); }

// ---------------- fp32 -> bf16 bulk convert (vectorized) ----------------
__global__ __launch_bounds__(256) void f32_to_bf16_k(const float* __restrict__ in,
                                                     __hip_bfloat16* __restrict__ out, int n8) {
    int i = blockIdx.x * 256 + threadIdx.x;
    if (i >= n8) return;
    const f32x4* p4 = reinterpret_cast<const f32x4*>(in) + (size_t)i * 2;
    f32x4 a = p4[0], b = p4[1];
    union { __hip_bfloat16 h[8]; uint4 u; } o;
    o.h[0] = __float2bfloat16(a[0]); o.h[1] = __float2bfloat16(a[1]);
    o.h[2] = __float2bfloat16(a[2]); o.h[3] = __float2bfloat16(a[3]);
    o.h[4] = __float2bfloat16(b[0]); o.h[5] = __float2bfloat16(b[1]);
    o.h[6] = __float2bfloat16(b[2]); o.h[7] = __float2bfloat16(b[3]);
    *reinterpret_cast<uint4*>(out + (size_t)i * 8) = o.u;
}

// ---------------- all 6 weight converts in ONE launch (blockIdx.y selects tensor) ----------------
__global__ __launch_bounds__(256)
void wconv6(const float* s0, const float* s1, const float* s2, const float* s3,
            const float* s4, const float* s5,
            __hip_bfloat16* d0, __hip_bfloat16* d1, __hip_bfloat16* d2,
            __hip_bfloat16* d3, __hip_bfloat16* d4, __hip_bfloat16* d5,
            int n0, int n1, int n2, int n3, int n4, int n5) {
    const float* src; __hip_bfloat16* dst; int n8;
    switch (blockIdx.y) {
        case 0: src = s0; dst = d0; n8 = n0; break;
        case 1: src = s1; dst = d1; n8 = n1; break;
        case 2: src = s2; dst = d2; n8 = n2; break;
        case 3: src = s3; dst = d3; n8 = n3; break;
        case 4: src = s4; dst = d4; n8 = n4; break;
        default: src = s5; dst = d5; n8 = n5; break;
    }
    int i = blockIdx.x * 256 + threadIdx.x;
    if (i >= n8) return;
    const f32x4* p4 = reinterpret_cast<const f32x4*>(src) + (size_t)i * 2;
    f32x4 a = p4[0], b = p4[1];
    union { __hip_bfloat16 h[8]; uint4 u; } o;
    o.h[0] = __float2bfloat16(a[0]); o.h[1] = __float2bfloat16(a[1]);
    o.h[2] = __float2bfloat16(a[2]); o.h[3] = __float2bfloat16(a[3]);
    o.h[4] = __float2bfloat16(b[0]); o.h[5] = __float2bfloat16(b[1]);
    o.h[6] = __float2bfloat16(b[2]); o.h[7] = __float2bfloat16(b[3]);
    *reinterpret_cast<uint4*>(dst + (size_t)i * 8) = o.u;
}

// ---- stage a full 128x64 bf16 tile (16 KB) with 256 threads (4 x gload16 each) ----
// Swizzle (R5-verified, conflicts=0): logical (r, colbyte c) lives at LDS byte
// r*128 + (c ^ ((r&7)<<4)); gload_lds writes linearly -> SOURCE col pre-XORed.
__device__ __forceinline__ void stage128(const __hip_bfloat16* src, int ldk, size_t row0,
                                         int k0, char* lds, int tid) {
    #pragma unroll
    for (int j = 0; j < 4; ++j) {
        int q = tid + 256 * j;               // 0..1023 16B-chunk id
        int row = q >> 3, c8 = q & 7;
        int cb = (c8 * 16) ^ ((row & 7) << 4);
        gload16((const char*)(src + (row0 + row) * (size_t)ldk + k0) + cb, lds + q * 16);
    }
}

// ================= 128x128 m97-style GEMM (single-buffer, multi-block overlap) =========
// MODE 0: z1 = silu(X@W^T + b)        -> bf16 (N=512, K=1024)
// MODE 1: out = (X@Dw^T + Db + HS@Cw^T + Cb) * sigmoid(X@Gw^T + Gb) -> f32 (N=1024)
// 4 waves (2x2), per-wave 64x64 quadrant, acc 4x4 f32x4 (dual acc in MODE 1).
// Simple loop: {sync; stage; sync; compute} — compiler drains vmcnt at barrier;
// latency hidden by 2-4 INDEPENDENT blocks/CU (m114), not source pipelining.
template<int MODE>
__global__ __launch_bounds__(256, 2)
void gemm128(const __hip_bfloat16* __restrict__ X, const __hip_bfloat16* __restrict__ W,
             const __hip_bfloat16* __restrict__ Gw, const __hip_bfloat16* __restrict__ HS,
             const __hip_bfloat16* __restrict__ CW,
             const float* __restrict__ bias, const float* __restrict__ bias2,
             const float* __restrict__ biasG,
             float* __restrict__ outF, __hip_bfloat16* __restrict__ outB) {
    constexpr int N = (MODE == 0) ? 512 : 1024;
    constexpr int nN = N / 128;
    __shared__ __align__(16) char Xs[16384];
    __shared__ __align__(16) char Ws[16384];
    __shared__ __align__(16) char Gs[(MODE == 1) ? 16384 : 16];

    const int nwg  = gridDim.x;
    const int orig = blockIdx.x;
    const int v    = (orig & 7) * (nwg >> 3) + (orig >> 3);   // XCD-bijective (nwg%8==0)
    const size_t m0 = (size_t)(v / nN) * 128;
    const int    n0 = (v % nN) * 128;
    const int tid = threadIdx.x, lane = tid & 63, wid = tid >> 6;
    const int wm = wid >> 1, wn = wid & 1;
    const int lr = lane & 15, lg = lane >> 4;

    auto frag = [&](const char* base, int R, int kk) -> bf16x8 {
        int cb = (kk * 64 + lg * 16) ^ ((R & 7) << 4);
        return *reinterpret_cast<const bf16x8*>(base + R * 128 + cb);
    };

    f32x4 accY[4][4] = {};
    f32x4 accG[(MODE == 1) ? 4 : 1][4] = {};

    for (int k0 = 0; k0 < 1024; k0 += 64) {
        __syncthreads();
        stage128(X, 1024, m0, k0, Xs, tid);
        stage128(W, 1024, (size_t)n0, k0, Ws, tid);
        if constexpr (MODE == 1) stage128(Gw, 1024, (size_t)n0, k0, Gs, tid);
        __syncthreads();
        #pragma unroll
        for (int kk = 0; kk < 2; ++kk) {
            bf16x8 af[4];
            #pragma unroll
            for (int m = 0; m < 4; ++m) af[m] = frag(Xs, wm*64 + m*16 + lr, kk);
            #pragma unroll
            for (int n = 0; n < 4; ++n) {
                bf16x8 bw = frag(Ws, wn*64 + n*16 + lr, kk);
                #pragma unroll
                for (int m = 0; m < 4; ++m)
                    accY[m][n] = __builtin_amdgcn_mfma_f32_16x16x32_bf16(af[m], bw, accY[m][n], 0, 0, 0);
                if constexpr (MODE == 1) {
                    bf16x8 bg = frag(Gs, wn*64 + n*16 + lr, kk);
                    #pragma unroll
                    for (int m = 0; m < 4; ++m)
                        accG[m][n] = __builtin_amdgcn_mfma_f32_16x16x32_bf16(af[m], bg, accG[m][n], 0, 0, 0);
                }
            }
        }
    }
    if constexpr (MODE == 1) {
        // C-phase: accY += HS[128x128-tile] @ Cw^T, 2 K-tiles
        for (int k0 = 0; k0 < 128; k0 += 64) {
            __syncthreads();
            stage128(HS, 128, m0, k0, Xs, tid);
            stage128(CW, 128, (size_t)n0, k0, Ws, tid);
            __syncthreads();
            #pragma unroll
            for (int kk = 0; kk < 2; ++kk) {
                bf16x8 af[4];
                #pragma unroll
                for (int m = 0; m < 4; ++m) af[m] = frag(Xs, wm*64 + m*16 + lr, kk);
                #pragma unroll
                for (int n = 0; n < 4; ++n) {
                    bf16x8 bw = frag(Ws, wn*64 + n*16 + lr, kk);
                    #pragma unroll
                    for (int m = 0; m < 4; ++m)
                        accY[m][n] = __builtin_amdgcn_mfma_f32_16x16x32_bf16(af[m], bw, accY[m][n], 0, 0, 0);
                }
            }
        }
    }

    // epilogue
    #pragma unroll
    for (int m = 0; m < 4; ++m)
        #pragma unroll
        for (int n = 0; n < 4; ++n)
            #pragma unroll
            for (int rr = 0; rr < 4; ++rr) {
                size_t row = m0 + wm*64 + m*16 + lg*4 + rr;
                int col = n0 + wn*64 + n*16 + lr;
                if constexpr (MODE == 0) {
                    float vv = accY[m][n][rr] + bias[col];
                    outB[row * N + col] = __float2bfloat16(vv * sigmoidf_(vv));
                } else {
                    float y = accY[m][n][rr] + bias[col] + bias2[col];
                    float g = accG[m][n][rr] + biasG[col];
                    outF[row * 1024 + col] = y * sigmoidf_(g);
                }
            }
}

// ---------------- u = (x@B_w^T + B_b) * sigmoid(z1@s_w2^T + s_b2)   [16384,128] ----------------
__global__ __launch_bounds__(256)
void gemm_u(const __hip_bfloat16* __restrict__ Z1, const __hip_bfloat16* __restrict__ W2,
            const float* __restrict__ b2,
            const __hip_bfloat16* __restrict__ X, const __hip_bfloat16* __restrict__ Bw,
            const float* __restrict__ Bb, __hip_bfloat16* __restrict__ U) {
    __shared__ __align__(16) char As[64 * 128];    // 64 rows x 128 B
    __shared__ __align__(16) char Bs[128 * 128];   // 128 rows x 128 B
    const int orig = blockIdx.x;                 // nwg = 256
    const int v = (orig & 7) * 32 + (orig >> 3);
    const int m0 = v * 64;
    const int tid = threadIdx.x;
    const int wid = tid >> 6, lane = tid & 63;
    const int wm = wid >> 1, wn = wid & 1;
    const int lr = lane & 15, lg = lane >> 4;
    const int srow = tid >> 3, sc8 = tid & 7;

    auto fragA = [&](int R, int kk) -> bf16x8 {
        int cb = (kk * 64 + lg * 16) ^ ((R & 7) << 4);
        return *reinterpret_cast<const bf16x8*>(As + R * 128 + cb);
    };
    auto fragB = [&](int R, int kk) -> bf16x8 {
        int cb = (kk * 64 + lg * 16) ^ ((R & 7) << 4);
        return *reinterpret_cast<const bf16x8*>(Bs + R * 128 + cb);
    };

    f32x4 accS[2][4] = {};
    for (int k0 = 0; k0 < 512; k0 += 64) {
        __syncthreads();
        #pragma unroll
        for (int j = 0; j < 2; ++j) {
            int row = srow + j * 32, q = tid + 256 * j;
            int cb = (sc8 * 16) ^ ((row & 7) << 4);
            gload16((const char*)&Z1[(size_t)(m0 + row) * 512 + k0] + cb, As + q * 16);
        }
        #pragma unroll
        for (int j = 0; j < 4; ++j) {
            int row = srow + j * 32, q = tid + 256 * j;
            int cb = (sc8 * 16) ^ ((row & 7) << 4);
            gload16((const char*)&W2[(size_t)row * 512 + k0] + cb, Bs + q * 16);
        }
        __syncthreads();
        #pragma unroll
        for (int kk = 0; kk < 2; ++kk) {
            bf16x8 af[2], bfr[4];
            #pragma unroll
            for (int m = 0; m < 2; ++m) af[m] = fragA(wm*32 + m*16 + lr, kk);
            #pragma unroll
            for (int n = 0; n < 4; ++n) bfr[n] = fragB(wn*64 + n*16 + lr, kk);
            #pragma unroll
            for (int m = 0; m < 2; ++m)
                #pragma unroll
                for (int n = 0; n < 4; ++n)
                    accS[m][n] = __builtin_amdgcn_mfma_f32_16x16x32_bf16(af[m], bfr[n], accS[m][n], 0, 0, 0);
        }
    }
    #pragma unroll
    for (int m = 0; m < 2; ++m)
        #pragma unroll
        for (int n = 0; n < 4; ++n)
            #pragma unroll
            for (int r = 0; r < 4; ++r) {
                int col = wn*64 + n*16 + lr;
                accS[m][n][r] = sigmoidf_(accS[m][n][r] + b2[col]);
            }
    f32x4 accU[2][4] = {};
    for (int k0 = 0; k0 < 1024; k0 += 64) {
        __syncthreads();
        #pragma unroll
        for (int j = 0; j < 2; ++j) {
            int row = srow + j * 32, q = tid + 256 * j;
            int cb = (sc8 * 16) ^ ((row & 7) << 4);
            gload16((const char*)&X[(size_t)(m0 + row) * 1024 + k0] + cb, As + q * 16);
        }
        #pragma unroll
        for (int j = 0; j < 4; ++j) {
            int row = srow + j * 32, q = tid + 256 * j;
            int cb = (sc8 * 16) ^ ((row & 7) << 4);
            gload16((const char*)&Bw[(size_t)row * 1024 + k0] + cb, Bs + q * 16);
        }
        __syncthreads();
        #pragma unroll
        for (int kk = 0; kk < 2; ++kk) {
            bf16x8 af[2], bfr[4];
            #pragma unroll
            for (int m = 0; m < 2; ++m) af[m] = fragA(wm*32 + m*16 + lr, kk);
            #pragma unroll
            for (int n = 0; n < 4; ++n) bfr[n] = fragB(wn*64 + n*16 + lr, kk);
            #pragma unroll
            for (int m = 0; m < 2; ++m)
                #pragma unroll
                for (int n = 0; n < 4; ++n)
                    accU[m][n] = __builtin_amdgcn_mfma_f32_16x16x32_bf16(af[m], bfr[n], accU[m][n], 0, 0, 0);
        }
    }
    #pragma unroll
    for (int m = 0; m < 2; ++m)
        #pragma unroll
        for (int n = 0; n < 4; ++n)
            #pragma unroll
            for (int r = 0; r < 4; ++r) {
                int row = m0 + wm*32 + m*16 + lg*4 + r;
                int col = wn*64 + n*16 + lr;
                float uval = (accU[m][n][r] + Bb[col]) * accS[m][n][r];
                U[(size_t)row * 128 + col] = __float2bfloat16(uval);
            }
}

// ---------------- P^8 column-wise: block j computes col j via 7 matvecs (fp32 exact) ---------
__global__ __launch_bounds__(128) void matpow8(const float* __restrict__ P,
                                               float* __restrict__ O) {
    __shared__ float Pl[128 * 132];
    __shared__ __align__(16) float v[2][128];
    const int tid = threadIdx.x, j = blockIdx.x;
    #pragma unroll 8
    for (int r = 0; r < 128; ++r) Pl[r * 132 + tid] = P[r * 128 + tid];
    v[0][tid] = P[tid * 128 + j];    // column j
    __syncthreads();
    int cur = 0;
    for (int it = 0; it < 7; ++it) {
        const f32x4* row = reinterpret_cast<const f32x4*>(&Pl[tid * 132]);
        const f32x4* hv  = reinterpret_cast<const f32x4*>(v[cur]);
        f32x4 s4 = {0.f, 0.f, 0.f, 0.f};
        #pragma unroll
        for (int k = 0; k < 32; ++k) s4 += row[k] * hv[k];
        v[cur ^ 1][tid] = s4[0] + s4[1] + s4[2] + s4[3];
        __syncthreads();
        cur ^= 1;
    }
    O[tid * 128 + j] = v[cur][tid];
}

// ---------------- chunked scan phase 1: local chunk-end states (zero init) ----------------
__global__ __launch_bounds__(128) void ssm_phase1(const float* __restrict__ A,
                                                  const __hip_bfloat16* __restrict__ u,
                                                  float* __restrict__ E) {
    __shared__ float Al[128 * 132];
    __shared__ __align__(16) float hbuf[2][128];
    const int tid = threadIdx.x;
    #pragma unroll 8
    for (int r = 0; r < 128; ++r) Al[r * 132 + tid] = A[r * 128 + tid];
    hbuf[0][tid] = 0.f;
    __syncthreads();
    const int b = blockIdx.x >> 5, c = blockIdx.x & 31;
    const __hip_bfloat16* up = u + ((size_t)b * 2048 + c * CHUNK) * 128;
    const f32x4* Arow = reinterpret_cast<const f32x4*>(&Al[tid * 132]);
    int cur = 0;
    for (int t = 0; t < CHUNK; ++t) {
        const f32x4* hv = reinterpret_cast<const f32x4*>(hbuf[cur]);
        f32x4 s4 = {0.f, 0.f, 0.f, 0.f};
        #pragma unroll
        for (int k = 0; k < 32; ++k) s4 += Arow[k] * hv[k];
        float val = s4[0] + s4[1] + s4[2] + s4[3] + __bfloat162float(up[t * 128 + tid]);
        hbuf[cur ^ 1][tid] = val;
        __syncthreads();
        cur ^= 1;
    }
    E[(size_t)blockIdx.x * 128 + tid] = hbuf[cur][tid];
}

// ---------------- phase 2: per-batch sequential combine across chunks with A^64 ----------------
__global__ __launch_bounds__(128) void ssm_phase2(const float* __restrict__ A64,
                                                  const float* __restrict__ E,
                                                  float* __restrict__ starts) {
    __shared__ float Al[128 * 132];
    __shared__ __align__(16) float st[2][128];
    const int tid = threadIdx.x;
    const int b = blockIdx.x;     // 8 blocks, one per batch
    #pragma unroll 8
    for (int r = 0; r < 128; ++r) Al[r * 132 + tid] = A64[r * 128 + tid];
    st[0][tid] = 0.f;
    __syncthreads();
    const f32x4* Arow = reinterpret_cast<const f32x4*>(&Al[tid * 132]);
    int cur = 0;
    for (int c = 0; c < NCHUNK; ++c) {
        starts[((size_t)b * NCHUNK + c) * 128 + tid] = st[cur][tid];
        const f32x4* hv = reinterpret_cast<const f32x4*>(st[cur]);
        f32x4 s4 = {0.f, 0.f, 0.f, 0.f};
        #pragma unroll
        for (int k = 0; k < 32; ++k) s4 += Arow[k] * hv[k];
        float val = s4[0] + s4[1] + s4[2] + s4[3] + E[((size_t)b * NCHUNK + c) * 128 + tid];
        st[cur ^ 1][tid] = val;
        __syncthreads();
        cur ^= 1;
    }
}

// ---------------- phase 3: re-run local scans from correct starts, emit hs (bf16) ----------------
__global__ __launch_bounds__(128) void ssm_phase3(const float* __restrict__ A,
                                                  const __hip_bfloat16* __restrict__ u,
                                                  const float* __restrict__ starts,
                                                  __hip_bfloat16* __restrict__ hs) {
    __shared__ float Al[128 * 132];
    __shared__ __align__(16) float hbuf[2][128];
    const int tid = threadIdx.x;
    #pragma unroll 8
    for (int r = 0; r < 128; ++r) Al[r * 132 + tid] = A[r * 128 + tid];
    hbuf[0][tid] = starts[(size_t)blockIdx.x * 128 + tid];
    __syncthreads();
    const int b = blockIdx.x >> 5, c = blockIdx.x & 31;
    const size_t tok0 = (size_t)b * 2048 + c * CHUNK;
    const __hip_bfloat16* up = u + tok0 * 128;
    const f32x4* Arow = reinterpret_cast<const f32x4*>(&Al[tid * 132]);
    int cur = 0;
    for (int t = 0; t < CHUNK; ++t) {
        const f32x4* hv = reinterpret_cast<const f32x4*>(hbuf[cur]);
        f32x4 s4 = {0.f, 0.f, 0.f, 0.f};
        #pragma unroll
        for (int k = 0; k < 32; ++k) s4 += Arow[k] * hv[k];
        float val = s4[0] + s4[1] + s4[2] + s4[3] + __bfloat162float(up[t * 128 + tid]);
        hs[(tok0 + t) * 128 + tid] = __float2bfloat16(val);
        hbuf[cur ^ 1][tid] = val;
        __syncthreads();
        cur ^= 1;
    }
}

// ---------------- host ----------------
extern "C" void kernel_launch(void* const* d_in, const int* in_sizes, int n_in,
                              void* d_out, int out_size, void* d_ws, size_t ws_size,
                              hipStream_t stream) {
    const float* x    = (const float*)d_in[0];
    const float* A    = (const float*)d_in[1];
    const float* B_w  = (const float*)d_in[2];
    const float* B_b  = (const float*)d_in[3];
    const float* C_w  = (const float*)d_in[4];
    const float* C_b  = (const float*)d_in[5];
    const float* D_w  = (const float*)d_in[6];
    const float* D_b  = (const float*)d_in[7];
    const float* s_w1 = (const float*)d_in[8];
    const float* s_b1 = (const float*)d_in[9];
    const float* s_w2 = (const float*)d_in[10];
    const float* s_b2 = (const float*)d_in[11];
    const float* g_w  = (const float*)d_in[12];
    const float* g_b  = (const float*)d_in[13];
    float* out = (float*)d_out;

    char* p = (char*)d_ws;
    auto alloc = [&](size_t n) { char* r = p; p += (n + 255) & ~(size_t)255; return r; };
    __hip_bfloat16* xb    = (__hip_bfloat16*)alloc((size_t)M_TOK * 1024 * 2);
    __hip_bfloat16* w1b   = (__hip_bfloat16*)alloc(512 * 1024 * 2);
    __hip_bfloat16* w2b   = (__hip_bfloat16*)alloc(128 * 512 * 2);
    __hip_bfloat16* Bwb   = (__hip_bfloat16*)alloc(128 * 1024 * 2);
    __hip_bfloat16* Cwb   = (__hip_bfloat16*)alloc(1024 * 128 * 2);
    __hip_bfloat16* Dwb   = (__hip_bfloat16*)alloc(1024 * 1024 * 2);
    __hip_bfloat16* gwb   = (__hip_bfloat16*)alloc(1024 * 1024 * 2);
    __hip_bfloat16* z1b   = (__hip_bfloat16*)alloc((size_t)M_TOK * 512 * 2);
    __hip_bfloat16* ub    = (__hip_bfloat16*)alloc((size_t)M_TOK * 128 * 2);
    __hip_bfloat16* hsb   = (__hip_bfloat16*)alloc((size_t)M_TOK * 128 * 2);
    float* pa       = (float*)alloc(128 * 128 * 4);
    float* pb       = (float*)alloc(128 * 128 * 4);
    float* Ebuf     = (float*)alloc(256 * 128 * 4);
    float* startbuf = (float*)alloc(256 * 128 * 4);

    // A^64 = (A^8)^8 via two column-matvec kernels (fp32 exact)
    matpow8<<<128, 128, 0, stream>>>(A,  pa);   // A^8
    matpow8<<<128, 128, 0, stream>>>(pa, pb);   // A^64

    // x -> bf16
    f32_to_bf16_k<<<dim3((M_TOK * 1024 / 8 + 255) / 256), dim3(256), 0, stream>>>(
        x, xb, M_TOK * 1024 / 8);
    // all weight converts, one launch
    wconv6<<<dim3(512, 6), dim3(256), 0, stream>>>(
        s_w1, s_w2, B_w, C_w, D_w, g_w,
        w1b, w2b, Bwb, Cwb, Dwb, gwb,
        512 * 1024 / 8, 128 * 512 / 8, 128 * 1024 / 8, 1024 * 128 / 8,
        1024 * 1024 / 8, 1024 * 1024 / 8);

    // z1 = silu(x @ s_w1^T + s_b1)   — 512 blocks (full chip)
    gemm128<0><<<dim3(512), dim3(256), 0, stream>>>(
        xb, w1b, nullptr, nullptr, nullptr, s_b1, nullptr, nullptr, nullptr, z1b);
    // u = (x @ B_w^T + B_b) * sigmoid(z1 @ s_w2^T + s_b2)
    gemm_u<<<dim3(256), dim3(256), 0, stream>>>(z1b, w2b, s_b2, xb, Bwb, B_b, ub);

    // chunked scan
    ssm_phase1<<<256, 128, 0, stream>>>(A, ub, Ebuf);
    ssm_phase2<<<8, 128, 0, stream>>>(pb, Ebuf, startbuf);
    ssm_phase3<<<256, 128, 0, stream>>>(A, ub, startbuf, hsb);

    // out = (x@D^T + Db + hs@C^T + Cb) * sigmoid(x@g^T + gb) — fused, 1024 blocks
    gemm128<1><<<dim3(1024), dim3(256), 0, stream>>>(
        xb, Dwb, gwb, hsb, Cwb, D_b, C_b, g_b, out, nullptr);
}

// Round 9
// 229.353 us; speedup vs baseline: 1.1574x; 1.0439x over previous
//
#include <hip/hip_runtime.h>
#include <hip/hip_bf16.h>

typedef __bf16 bf16x8 __attribute__((ext_vector_type(8)));
typedef float f32x4 __attribute__((ext_vector_type(4)));

#define M_TOK 16384   // 8 * 2048 tokens
#define CHUNK 64
#define NCHUNK 32     // 2048 / 64

__device__ __forceinline__ void gload16(const void* g, void* l) {
    __builtin_amdgcn_global_load_lds(
        (const __attribute__((address_space(1))) void*)g,
        (__attribute__((address_space(3))) void*)l, 16, 0, 0);
}

__device__ __forceinline__ float sigmoidf_(float v) { return 1.f / (1.f + __expf(-v)); }

// ---------------- fp32 -> bf16 bulk convert (vectorized) ----------------
__global__ __launch_bounds__(256) void f32_to_bf16_k(const float* __restrict__ in,
                                                     __hip_bfloat16* __restrict__ out, int n8) {
    int i = blockIdx.x * 256 + threadIdx.x;
    if (i >= n8) return;
    const f32x4* p4 = reinterpret_cast<const f32x4*>(in) + (size_t)i * 2;
    f32x4 a = p4[0], b = p4[1];
    union { __hip_bfloat16 h[8]; uint4 u; } o;
    o.h[0] = __float2bfloat16(a[0]); o.h[1] = __float2bfloat16(a[1]);
    o.h[2] = __float2bfloat16(a[2]); o.h[3] = __float2bfloat16(a[3]);
    o.h[4] = __float2bfloat16(b[0]); o.h[5] = __float2bfloat16(b[1]);
    o.h[6] = __float2bfloat16(b[2]); o.h[7] = __float2bfloat16(b[3]);
    *reinterpret_cast<uint4*>(out + (size_t)i * 8) = o.u;
}

// ---------------- all 6 weight converts in ONE launch (blockIdx.y selects tensor) ----------------
__global__ __launch_bounds__(256)
void wconv6(const float* s0, const float* s1, const float* s2, const float* s3,
            const float* s4, const float* s5,
            __hip_bfloat16* d0, __hip_bfloat16* d1, __hip_bfloat16* d2,
            __hip_bfloat16* d3, __hip_bfloat16* d4, __hip_bfloat16* d5,
            int n0, int n1, int n2, int n3, int n4, int n5) {
    const float* src; __hip_bfloat16* dst; int n8;
    switch (blockIdx.y) {
        case 0: src = s0; dst = d0; n8 = n0; break;
        case 1: src = s1; dst = d1; n8 = n1; break;
        case 2: src = s2; dst = d2; n8 = n2; break;
        case 3: src = s3; dst = d3; n8 = n3; break;
        case 4: src = s4; dst = d4; n8 = n4; break;
        default: src = s5; dst = d5; n8 = n5; break;
    }
    int i = blockIdx.x * 256 + threadIdx.x;
    if (i >= n8) return;
    const f32x4* p4 = reinterpret_cast<const f32x4*>(src) + (size_t)i * 2;
    f32x4 a = p4[0], b = p4[1];
    union { __hip_bfloat16 h[8]; uint4 u; } o;
    o.h[0] = __float2bfloat16(a[0]); o.h[1] = __float2bfloat16(a[1]);
    o.h[2] = __float2bfloat16(a[2]); o.h[3] = __float2bfloat16(a[3]);
    o.h[4] = __float2bfloat16(b[0]); o.h[5] = __float2bfloat16(b[1]);
    o.h[6] = __float2bfloat16(b[2]); o.h[7] = __float2bfloat16(b[3]);
    *reinterpret_cast<uint4*>(dst + (size_t)i * 8) = o.u;
}

// ---- stage a full 128x64 bf16 tile (16 KB) with 256 threads (4 x gload16 each) ----
// Swizzle (R5-verified, conflicts=0): logical (r, colbyte c) lives at LDS byte
// r*128 + (c ^ ((r&7)<<4)); gload_lds writes linearly -> SOURCE col pre-XORed.
__device__ __forceinline__ void stage128(const __hip_bfloat16* src, int ldk, size_t row0,
                                         int k0, char* lds, int tid) {
    #pragma unroll
    for (int j = 0; j < 4; ++j) {
        int q = tid + 256 * j;               // 0..1023 16B-chunk id
        int row = q >> 3, c8 = q & 7;
        int cb = (c8 * 16) ^ ((row & 7) << 4);
        gload16((const char*)(src + (row0 + row) * (size_t)ldk + k0) + cb, lds + q * 16);
    }
}

// ================= 128x128 m97-style GEMM (single-buffer, multi-block overlap) =========
// MODE 0: z1 = silu(X@W^T + b)        -> bf16 (N=512, K=1024)
// MODE 1: out = (X@Dw^T + Db + HS@Cw^T + Cb) * sigmoid(X@Gw^T + Gb) -> f32 (N=1024)
// 930 TF measured (R7) = m97-structure ceiling; latency hidden by 2 independent
// blocks/CU (m114), not source pipelining. Do not re-add manual vmcnt (R4/R6 null).
template<int MODE>
__global__ __launch_bounds__(256, 2)
void gemm128(const __hip_bfloat16* __restrict__ X, const __hip_bfloat16* __restrict__ W,
             const __hip_bfloat16* __restrict__ Gw, const __hip_bfloat16* __restrict__ HS,
             const __hip_bfloat16* __restrict__ CW,
             const float* __restrict__ bias, const float* __restrict__ bias2,
             const float* __restrict__ biasG,
             float* __restrict__ outF, __hip_bfloat16* __restrict__ outB) {
    constexpr int N = (MODE == 0) ? 512 : 1024;
    constexpr int nN = N / 128;
    __shared__ __align__(16) char Xs[16384];
    __shared__ __align__(16) char Ws[16384];
    __shared__ __align__(16) char Gs[(MODE == 1) ? 16384 : 16];

    const int nwg  = gridDim.x;
    const int orig = blockIdx.x;
    const int v    = (orig & 7) * (nwg >> 3) + (orig >> 3);   // XCD-bijective (nwg%8==0)
    const size_t m0 = (size_t)(v / nN) * 128;
    const int    n0 = (v % nN) * 128;
    const int tid = threadIdx.x, lane = tid & 63, wid = tid >> 6;
    const int wm = wid >> 1, wn = wid & 1;
    const int lr = lane & 15, lg = lane >> 4;

    auto frag = [&](const char* base, int R, int kk) -> bf16x8 {
        int cb = (kk * 64 + lg * 16) ^ ((R & 7) << 4);
        return *reinterpret_cast<const bf16x8*>(base + R * 128 + cb);
    };

    f32x4 accY[4][4] = {};
    f32x4 accG[(MODE == 1) ? 4 : 1][4] = {};

    for (int k0 = 0; k0 < 1024; k0 += 64) {
        __syncthreads();
        stage128(X, 1024, m0, k0, Xs, tid);
        stage128(W, 1024, (size_t)n0, k0, Ws, tid);
        if constexpr (MODE == 1) stage128(Gw, 1024, (size_t)n0, k0, Gs, tid);
        __syncthreads();
        #pragma unroll
        for (int kk = 0; kk < 2; ++kk) {
            bf16x8 af[4];
            #pragma unroll
            for (int m = 0; m < 4; ++m) af[m] = frag(Xs, wm*64 + m*16 + lr, kk);
            #pragma unroll
            for (int n = 0; n < 4; ++n) {
                bf16x8 bw = frag(Ws, wn*64 + n*16 + lr, kk);
                #pragma unroll
                for (int m = 0; m < 4; ++m)
                    accY[m][n] = __builtin_amdgcn_mfma_f32_16x16x32_bf16(af[m], bw, accY[m][n], 0, 0, 0);
                if constexpr (MODE == 1) {
                    bf16x8 bg = frag(Gs, wn*64 + n*16 + lr, kk);
                    #pragma unroll
                    for (int m = 0; m < 4; ++m)
                        accG[m][n] = __builtin_amdgcn_mfma_f32_16x16x32_bf16(af[m], bg, accG[m][n], 0, 0, 0);
                }
            }
        }
    }
    if constexpr (MODE == 1) {
        // C-phase: accY += HS[128x128-tile] @ Cw^T, 2 K-tiles
        for (int k0 = 0; k0 < 128; k0 += 64) {
            __syncthreads();
            stage128(HS, 128, m0, k0, Xs, tid);
            stage128(CW, 128, (size_t)n0, k0, Ws, tid);
            __syncthreads();
            #pragma unroll
            for (int kk = 0; kk < 2; ++kk) {
                bf16x8 af[4];
                #pragma unroll
                for (int m = 0; m < 4; ++m) af[m] = frag(Xs, wm*64 + m*16 + lr, kk);
                #pragma unroll
                for (int n = 0; n < 4; ++n) {
                    bf16x8 bw = frag(Ws, wn*64 + n*16 + lr, kk);
                    #pragma unroll
                    for (int m = 0; m < 4; ++m)
                        accY[m][n] = __builtin_amdgcn_mfma_f32_16x16x32_bf16(af[m], bw, accY[m][n], 0, 0, 0);
                }
            }
        }
    }

    // epilogue
    #pragma unroll
    for (int m = 0; m < 4; ++m)
        #pragma unroll
        for (int n = 0; n < 4; ++n)
            #pragma unroll
            for (int rr = 0; rr < 4; ++rr) {
                size_t row = m0 + wm*64 + m*16 + lg*4 + rr;
                int col = n0 + wn*64 + n*16 + lr;
                if constexpr (MODE == 0) {
                    float vv = accY[m][n][rr] + bias[col];
                    outB[row * N + col] = __float2bfloat16(vv * sigmoidf_(vv));
                } else {
                    float y = accY[m][n][rr] + bias[col] + bias2[col];
                    float g = accG[m][n][rr] + biasG[col];
                    outF[row * 1024 + col] = y * sigmoidf_(g);
                }
            }
}

// ---------------- u = (x@B_w^T + B_b) * sigmoid(z1@s_w2^T + s_b2)   [16384,128] ----------------
__global__ __launch_bounds__(256)
void gemm_u(const __hip_bfloat16* __restrict__ Z1, const __hip_bfloat16* __restrict__ W2,
            const float* __restrict__ b2,
            const __hip_bfloat16* __restrict__ X, const __hip_bfloat16* __restrict__ Bw,
            const float* __restrict__ Bb, __hip_bfloat16* __restrict__ U) {
    __shared__ __align__(16) char As[64 * 128];    // 64 rows x 128 B
    __shared__ __align__(16) char Bs[128 * 128];   // 128 rows x 128 B
    const int orig = blockIdx.x;                 // nwg = 256
    const int v = (orig & 7) * 32 + (orig >> 3);
    const int m0 = v * 64;
    const int tid = threadIdx.x;
    const int wid = tid >> 6, lane = tid & 63;
    const int wm = wid >> 1, wn = wid & 1;
    const int lr = lane & 15, lg = lane >> 4;
    const int srow = tid >> 3, sc8 = tid & 7;

    auto fragA = [&](int R, int kk) -> bf16x8 {
        int cb = (kk * 64 + lg * 16) ^ ((R & 7) << 4);
        return *reinterpret_cast<const bf16x8*>(As + R * 128 + cb);
    };
    auto fragB = [&](int R, int kk) -> bf16x8 {
        int cb = (kk * 64 + lg * 16) ^ ((R & 7) << 4);
        return *reinterpret_cast<const bf16x8*>(Bs + R * 128 + cb);
    };

    f32x4 accS[2][4] = {};
    for (int k0 = 0; k0 < 512; k0 += 64) {
        __syncthreads();
        #pragma unroll
        for (int j = 0; j < 2; ++j) {
            int row = srow + j * 32, q = tid + 256 * j;
            int cb = (sc8 * 16) ^ ((row & 7) << 4);
            gload16((const char*)&Z1[(size_t)(m0 + row) * 512 + k0] + cb, As + q * 16);
        }
        #pragma unroll
        for (int j = 0; j < 4; ++j) {
            int row = srow + j * 32, q = tid + 256 * j;
            int cb = (sc8 * 16) ^ ((row & 7) << 4);
            gload16((const char*)&W2[(size_t)row * 512 + k0] + cb, Bs + q * 16);
        }
        __syncthreads();
        #pragma unroll
        for (int kk = 0; kk < 2; ++kk) {
            bf16x8 af[2], bfr[4];
            #pragma unroll
            for (int m = 0; m < 2; ++m) af[m] = fragA(wm*32 + m*16 + lr, kk);
            #pragma unroll
            for (int n = 0; n < 4; ++n) bfr[n] = fragB(wn*64 + n*16 + lr, kk);
            #pragma unroll
            for (int m = 0; m < 2; ++m)
                #pragma unroll
                for (int n = 0; n < 4; ++n)
                    accS[m][n] = __builtin_amdgcn_mfma_f32_16x16x32_bf16(af[m], bfr[n], accS[m][n], 0, 0, 0);
        }
    }
    #pragma unroll
    for (int m = 0; m < 2; ++m)
        #pragma unroll
        for (int n = 0; n < 4; ++n)
            #pragma unroll
            for (int r = 0; r < 4; ++r) {
                int col = wn*64 + n*16 + lr;
                accS[m][n][r] = sigmoidf_(accS[m][n][r] + b2[col]);
            }
    f32x4 accU[2][4] = {};
    for (int k0 = 0; k0 < 1024; k0 += 64) {
        __syncthreads();
        #pragma unroll
        for (int j = 0; j < 2; ++j) {
            int row = srow + j * 32, q = tid + 256 * j;
            int cb = (sc8 * 16) ^ ((row & 7) << 4);
            gload16((const char*)&X[(size_t)(m0 + row) * 1024 + k0] + cb, As + q * 16);
        }
        #pragma unroll
        for (int j = 0; j < 4; ++j) {
            int row = srow + j * 32, q = tid + 256 * j;
            int cb = (sc8 * 16) ^ ((row & 7) << 4);
            gload16((const char*)&Bw[(size_t)row * 1024 + k0] + cb, Bs + q * 16);
        }
        __syncthreads();
        #pragma unroll
        for (int kk = 0; kk < 2; ++kk) {
            bf16x8 af[2], bfr[4];
            #pragma unroll
            for (int m = 0; m < 2; ++m) af[m] = fragA(wm*32 + m*16 + lr, kk);
            #pragma unroll
            for (int n = 0; n < 4; ++n) bfr[n] = fragB(wn*64 + n*16 + lr, kk);
            #pragma unroll
            for (int m = 0; m < 2; ++m)
                #pragma unroll
                for (int n = 0; n < 4; ++n)
                    accU[m][n] = __builtin_amdgcn_mfma_f32_16x16x32_bf16(af[m], bfr[n], accU[m][n], 0, 0, 0);
        }
    }
    #pragma unroll
    for (int m = 0; m < 2; ++m)
        #pragma unroll
        for (int n = 0; n < 4; ++n)
            #pragma unroll
            for (int r = 0; r < 4; ++r) {
                int row = m0 + wm*32 + m*16 + lg*4 + r;
                int col = wn*64 + n*16 + lr;
                float uval = (accU[m][n][r] + Bb[col]) * accS[m][n][r];
                U[(size_t)row * 128 + col] = __float2bfloat16(uval);
            }
}

// ---------------- P^8 column-wise, P-row in REGISTERS (128 VGPR), v in LDS ---------
__global__ __launch_bounds__(128, 1) void matpow8(const float* __restrict__ P,
                                                  float* __restrict__ O) {
    __shared__ __align__(16) float v[2][128];
    const int tid = threadIdx.x, col = blockIdx.x;
    f32x4 pr[32];
    #pragma unroll
    for (int k = 0; k < 32; ++k) pr[k] = *reinterpret_cast<const f32x4*>(&P[tid * 128 + k * 4]);
    v[0][tid] = P[tid * 128 + col];    // column col
    __syncthreads();
    int cur = 0;
    for (int it = 0; it < 7; ++it) {
        const f32x4* hv = reinterpret_cast<const f32x4*>(v[cur]);
        f32x4 s0{}, s1{}, s2{}, s3{};
        #pragma unroll
        for (int k = 0; k < 32; k += 4) {
            s0 += pr[k]     * hv[k];
            s1 += pr[k + 1] * hv[k + 1];
            s2 += pr[k + 2] * hv[k + 2];
            s3 += pr[k + 3] * hv[k + 3];
        }
        f32x4 ss = (s0 + s1) + (s2 + s3);
        v[cur ^ 1][tid] = ss[0] + ss[1] + ss[2] + ss[3];
        __syncthreads();
        cur ^= 1;
    }
    O[tid * 128 + col] = v[cur][tid];
}

// ---------------- scan phase 1: local chunk-end states; A-row in REGISTERS ----------------
// Per step: 32 broadcast LDS reads (h) + 128 FMA via 4 independent accumulators
// (breaks the dependent-FMA chain) + 1 write + barrier. u pre-staged to LDS.
__global__ __launch_bounds__(128, 1) void ssm_phase1(const float* __restrict__ A,
                                                     const __hip_bfloat16* __restrict__ u,
                                                     float* __restrict__ E) {
    __shared__ __align__(16) float hb[2][128];
    __shared__ __align__(16) __hip_bfloat16 uL[CHUNK * 128];   // 16 KB
    const int tid = threadIdx.x;
    f32x4 ar[32];
    #pragma unroll
    for (int k = 0; k < 32; ++k) ar[k] = *reinterpret_cast<const f32x4*>(&A[tid * 128 + k * 4]);
    const int b = blockIdx.x >> 5, c = blockIdx.x & 31;
    const __hip_bfloat16* up = u + ((size_t)b * 2048 + c * CHUNK) * 128;
    #pragma unroll
    for (int q = 0; q < 8; ++q)
        gload16(up + ((size_t)(q * 128 + tid)) * 8, &uL[(q * 128 + tid) * 8]);
    hb[0][tid] = 0.f;
    __syncthreads();
    int cur = 0;
    for (int t = 0; t < CHUNK; ++t) {
        const f32x4* hv = reinterpret_cast<const f32x4*>(hb[cur]);
        f32x4 s0{}, s1{}, s2{}, s3{};
        #pragma unroll
        for (int k = 0; k < 32; k += 4) {
            s0 += ar[k]     * hv[k];
            s1 += ar[k + 1] * hv[k + 1];
            s2 += ar[k + 2] * hv[k + 2];
            s3 += ar[k + 3] * hv[k + 3];
        }
        f32x4 ss = (s0 + s1) + (s2 + s3);
        float val = ss[0] + ss[1] + ss[2] + ss[3] + __bfloat162float(uL[t * 128 + tid]);
        hb[cur ^ 1][tid] = val;
        __syncthreads();
        cur ^= 1;
    }
    E[(size_t)blockIdx.x * 128 + tid] = hb[cur][tid];
}

// ---------------- phase 2: per-batch combine across chunks; A64-row in REGISTERS ---------
__global__ __launch_bounds__(128, 1) void ssm_phase2(const float* __restrict__ A64,
                                                     const float* __restrict__ E,
                                                     float* __restrict__ starts) {
    __shared__ __align__(16) float st[2][128];
    __shared__ __align__(16) float El[NCHUNK * 128];   // 16 KB
    const int tid = threadIdx.x, b = blockIdx.x;       // 8 blocks
    f32x4 ar[32];
    #pragma unroll
    for (int k = 0; k < 32; ++k) ar[k] = *reinterpret_cast<const f32x4*>(&A64[tid * 128 + k * 4]);
    const f32x4* Eg = reinterpret_cast<const f32x4*>(E + (size_t)b * NCHUNK * 128);
    #pragma unroll
    for (int q = 0; q < 8; ++q)
        reinterpret_cast<f32x4*>(El)[q * 128 + tid] = Eg[q * 128 + tid];
    st[0][tid] = 0.f;
    __syncthreads();
    int cur = 0;
    for (int c = 0; c < NCHUNK; ++c) {
        starts[((size_t)b * NCHUNK + c) * 128 + tid] = st[cur][tid];
        const f32x4* hv = reinterpret_cast<const f32x4*>(st[cur]);
        f32x4 s0{}, s1{}, s2{}, s3{};
        #pragma unroll
        for (int k = 0; k < 32; k += 4) {
            s0 += ar[k]     * hv[k];
            s1 += ar[k + 1] * hv[k + 1];
            s2 += ar[k + 2] * hv[k + 2];
            s3 += ar[k + 3] * hv[k + 3];
        }
        f32x4 ss = (s0 + s1) + (s2 + s3);
        float val = ss[0] + ss[1] + ss[2] + ss[3] + El[c * 128 + tid];
        st[cur ^ 1][tid] = val;
        __syncthreads();
        cur ^= 1;
    }
}

// ---------------- phase 3: re-run local scans from starts, emit hs; A in REGISTERS ---------
__global__ __launch_bounds__(128, 1) void ssm_phase3(const float* __restrict__ A,
                                                     const __hip_bfloat16* __restrict__ u,
                                                     const float* __restrict__ starts,
                                                     __hip_bfloat16* __restrict__ hs) {
    __shared__ __align__(16) float hb[2][128];
    __shared__ __align__(16) __hip_bfloat16 uL[CHUNK * 128];   // 16 KB
    const int tid = threadIdx.x;
    f32x4 ar[32];
    #pragma unroll
    for (int k = 0; k < 32; ++k) ar[k] = *reinterpret_cast<const f32x4*>(&A[tid * 128 + k * 4]);
    const int b = blockIdx.x >> 5, c = blockIdx.x & 31;
    const size_t tok0 = (size_t)b * 2048 + c * CHUNK;
    const __hip_bfloat16* up = u + tok0 * 128;
    #pragma unroll
    for (int q = 0; q < 8; ++q)
        gload16(up + ((size_t)(q * 128 + tid)) * 8, &uL[(q * 128 + tid) * 8]);
    hb[0][tid] = starts[(size_t)blockIdx.x * 128 + tid];
    __syncthreads();
    int cur = 0;
    for (int t = 0; t < CHUNK; ++t) {
        const f32x4* hv = reinterpret_cast<const f32x4*>(hb[cur]);
        f32x4 s0{}, s1{}, s2{}, s3{};
        #pragma unroll
        for (int k = 0; k < 32; k += 4) {
            s0 += ar[k]     * hv[k];
            s1 += ar[k + 1] * hv[k + 1];
            s2 += ar[k + 2] * hv[k + 2];
            s3 += ar[k + 3] * hv[k + 3];
        }
        f32x4 ss = (s0 + s1) + (s2 + s3);
        float val = ss[0] + ss[1] + ss[2] + ss[3] + __bfloat162float(uL[t * 128 + tid]);
        hs[(tok0 + t) * 128 + tid] = __float2bfloat16(val);
        hb[cur ^ 1][tid] = val;
        __syncthreads();
        cur ^= 1;
    }
}

// ---------------- host ----------------
extern "C" void kernel_launch(void* const* d_in, const int* in_sizes, int n_in,
                              void* d_out, int out_size, void* d_ws, size_t ws_size,
                              hipStream_t stream) {
    const float* x    = (const float*)d_in[0];
    const float* A    = (const float*)d_in[1];
    const float* B_w  = (const float*)d_in[2];
    const float* B_b  = (const float*)d_in[3];
    const float* C_w  = (const float*)d_in[4];
    const float* C_b  = (const float*)d_in[5];
    const float* D_w  = (const float*)d_in[6];
    const float* D_b  = (const float*)d_in[7];
    const float* s_w1 = (const float*)d_in[8];
    const float* s_b1 = (const float*)d_in[9];
    const float* s_w2 = (const float*)d_in[10];
    const float* s_b2 = (const float*)d_in[11];
    const float* g_w  = (const float*)d_in[12];
    const float* g_b  = (const float*)d_in[13];
    float* out = (float*)d_out;

    char* p = (char*)d_ws;
    auto alloc = [&](size_t n) { char* r = p; p += (n + 255) & ~(size_t)255; return r; };
    __hip_bfloat16* xb    = (__hip_bfloat16*)alloc((size_t)M_TOK * 1024 * 2);
    __hip_bfloat16* w1b   = (__hip_bfloat16*)alloc(512 * 1024 * 2);
    __hip_bfloat16* w2b   = (__hip_bfloat16*)alloc(128 * 512 * 2);
    __hip_bfloat16* Bwb   = (__hip_bfloat16*)alloc(128 * 1024 * 2);
    __hip_bfloat16* Cwb   = (__hip_bfloat16*)alloc(1024 * 128 * 2);
    __hip_bfloat16* Dwb   = (__hip_bfloat16*)alloc(1024 * 1024 * 2);
    __hip_bfloat16* gwb   = (__hip_bfloat16*)alloc(1024 * 1024 * 2);
    __hip_bfloat16* z1b   = (__hip_bfloat16*)alloc((size_t)M_TOK * 512 * 2);
    __hip_bfloat16* ub    = (__hip_bfloat16*)alloc((size_t)M_TOK * 128 * 2);
    __hip_bfloat16* hsb   = (__hip_bfloat16*)alloc((size_t)M_TOK * 128 * 2);
    float* pa       = (float*)alloc(128 * 128 * 4);
    float* pb       = (float*)alloc(128 * 128 * 4);
    float* Ebuf     = (float*)alloc(256 * 128 * 4);
    float* startbuf = (float*)alloc(256 * 128 * 4);

    // A^64 = (A^8)^8 via two column-matvec kernels (fp32 exact)
    matpow8<<<128, 128, 0, stream>>>(A,  pa);   // A^8
    matpow8<<<128, 128, 0, stream>>>(pa, pb);   // A^64

    // x -> bf16
    f32_to_bf16_k<<<dim3((M_TOK * 1024 / 8 + 255) / 256), dim3(256), 0, stream>>>(
        x, xb, M_TOK * 1024 / 8);
    // all weight converts, one launch
    wconv6<<<dim3(512, 6), dim3(256), 0, stream>>>(
        s_w1, s_w2, B_w, C_w, D_w, g_w,
        w1b, w2b, Bwb, Cwb, Dwb, gwb,
        512 * 1024 / 8, 128 * 512 / 8, 128 * 1024 / 8, 1024 * 128 / 8,
        1024 * 1024 / 8, 1024 * 1024 / 8);

    // z1 = silu(x @ s_w1^T + s_b1)   — 512 blocks (full chip)
    gemm128<0><<<dim3(512), dim3(256), 0, stream>>>(
        xb, w1b, nullptr, nullptr, nullptr, s_b1, nullptr, nullptr, nullptr, z1b);
    // u = (x @ B_w^T + B_b) * sigmoid(z1 @ s_w2^T + s_b2)
    gemm_u<<<dim3(256), dim3(256), 0, stream>>>(z1b, w2b, s_b2, xb, Bwb, B_b, ub);

    // chunked scan (A-in-registers)
    ssm_phase1<<<256, 128, 0, stream>>>(A, ub, Ebuf);
    ssm_phase2<<<8, 128, 0, stream>>>(pb, Ebuf, startbuf);
    ssm_phase3<<<256, 128, 0, stream>>>(A, ub, startbuf, hsb);

    // out = (x@D^T + Db + hs@C^T + Cb) * sigmoid(x@g^T + gb) — fused, 1024 blocks
    gemm128<1><<<dim3(1024), dim3(256), 0, stream>>>(
        xb, Dwb, gwb, hsb, Cwb, D_b, C_b, g_b, out, nullptr);
}